// Round 5
// baseline (115.804 us; speedup 1.0000x reference)
//
#include <hip/hip_runtime.h>
#include <math.h>

// E8 quantizer, fully-factored exp + 2-points-per-thread MLP version.
// Math identical to round-3 kernel (32 exp2 + ~190 VALU per point); this
// round restructures for memory-level parallelism: each thread loads two
// points (4x float4 issued before any compute) and runs two independent
// ALU chains, stores via nontemporal writes (output is write-only).
// Uses native clang vector type (ext_vector_type) because
// __builtin_nontemporal_store rejects HIP_vector_type<float,4>.

static constexpr float TEMP = 0.3f;

typedef float vfloat4 __attribute__((ext_vector_type(4)));

__device__ __forceinline__ float fexp2(float v) { return __builtin_amdgcn_exp2f(v); }
__device__ __forceinline__ float frcp(float v) { return __builtin_amdgcn_rcpf(v); }

__device__ __forceinline__ void e8_point(const float xv[8], float outv[8]) {
    const float K  = 2.0f * 1.44269504088896340736f / TEMP;  // exp2 units
    const float Kh = 0.5f * K;
    float nrm2 = 0.f;
#pragma unroll
    for (int k = 0; k < 8; ++k) nrm2 = fmaf(xv[k], xv[k], nrm2);
    const float r  = sqrtf(nrm2);
    const float C  = -1.41421356237309515f * r * K;
    const float C2 = 0.5f * C;
    const float C4 = 0.25f * C;

    // ---- per-pair exponentials for half-roots (16 exps) ----
    float e01[4], e23[4], e45[4], e67[4];
    {
        const float u01 = xv[0] + xv[1], v01 = xv[1] - xv[0];
        const float u23 = xv[2] + xv[3], v23 = xv[3] - xv[2];
        const float u45 = xv[4] + xv[5], v45 = xv[5] - xv[4];
        const float u67 = xv[6] + xv[7], v67 = xv[7] - xv[6];
        e01[0] = fexp2(fmaf(u01, Kh, C4)); e01[3] = fexp2(fmaf(-u01, Kh, C4));
        e01[1] = fexp2(fmaf(v01, Kh, C4)); e01[2] = fexp2(fmaf(-v01, Kh, C4));
        e23[0] = fexp2(fmaf(u23, Kh, C4)); e23[3] = fexp2(fmaf(-u23, Kh, C4));
        e23[1] = fexp2(fmaf(v23, Kh, C4)); e23[2] = fexp2(fmaf(-v23, Kh, C4));
        e45[0] = fexp2(fmaf(u45, Kh, C4)); e45[3] = fexp2(fmaf(-u45, Kh, C4));
        e45[1] = fexp2(fmaf(v45, Kh, C4)); e45[2] = fexp2(fmaf(-v45, Kh, C4));
        e67[0] = fexp2(fmaf(u67, Kh, C4)); e67[3] = fexp2(fmaf(-u67, Kh, C4));
        e67[1] = fexp2(fmaf(v67, Kh, C4)); e67[2] = fexp2(fmaf(-v67, Kh, C4));
    }

    const float G01e = e01[0] + e01[3], G01o = e01[1] + e01[2];
    const float G23e = e23[0] + e23[3], G23o = e23[1] + e23[2];
    const float G45e = e45[0] + e45[3], G45o = e45[1] + e45[2];
    const float G67e = e67[0] + e67[3], G67o = e67[1] + e67[2];
    const float dA01 = e01[0] - e01[3], dB01 = e01[2] - e01[1];
    const float dA23 = e23[0] - e23[3], dB23 = e23[2] - e23[1];
    const float dA45 = e45[0] - e45[3], dB45 = e45[2] - e45[1];
    const float dA67 = e67[0] - e67[3], dB67 = e67[2] - e67[1];

    const float SAe = fmaf(G01e, G23e, G01o * G23o);
    const float SAo = fmaf(G01e, G23o, G01o * G23e);
    const float SBe = fmaf(G45e, G67e, G45o * G67o);
    const float SBo = fmaf(G45e, G67o, G45o * G67e);
    const float s2sum = fmaf(SAe, SBe, SAo * SBo);

    const float M01e = fmaf(G23e, SBe, G23o * SBo), M01o = fmaf(G23e, SBo, G23o * SBe);
    const float M23e = fmaf(G01e, SBe, G01o * SBo), M23o = fmaf(G01e, SBo, G01o * SBe);
    const float M45e = fmaf(G67e, SAe, G67o * SAo), M45o = fmaf(G67e, SAo, G67o * SAe);
    const float M67e = fmaf(G45e, SAe, G45o * SAo), M67o = fmaf(G45e, SAo, G45o * SAe);

    float comp[8];
    {
        const float t0 = dA01 * M01e, t1 = dB01 * M01o;
        comp[0] = t0 + t1; comp[1] = t0 - t1;
        const float t2 = dA23 * M23e, t3 = dB23 * M23o;
        comp[2] = t2 + t3; comp[3] = t2 - t3;
        const float t4 = dA45 * M45e, t5 = dB45 * M45o;
        comp[4] = t4 + t5; comp[5] = t4 - t5;
        const float t6 = dA67 * M67e, t7 = dB67 * M67o;
        comp[6] = t6 + t7; comp[7] = t6 - t7;
    }

    // ---- 112 integer roots via 16 factored exps ----
    float P[8], D[8];
#pragma unroll
    for (int i = 0; i < 8; ++i) {
        const float ep = fexp2(fmaf(xv[i],  K, C2));
        const float em = fexp2(fmaf(-xv[i], K, C2));
        P[i] = ep + em;
        D[i] = ep - em;
    }
    float suf[9];
    suf[8] = 0.f;
#pragma unroll
    for (int i = 7; i >= 0; --i) suf[i] = suf[i + 1] + P[i];
    float pre = 0.f, ssum_int = 0.f;
    float acc[8];
#pragma unroll
    for (int i = 0; i < 8; ++i) {
        const float Q = pre + suf[i + 1];             // sum_{j != i} P[j]
        acc[i] = D[i] * Q;
        ssum_int = fmaf(P[i], suf[i + 1], ssum_int);  // sum_{i<j} P_i P_j
        pre += P[i];
    }

    const float ssum = ssum_int + s2sum;
    const float inv  = frcp(ssum);
#pragma unroll
    for (int k = 0; k < 8; ++k) {
        const float total = fmaf(0.5f, comp[k], acc[k]);
        const float q = total * inv;
        outv[k] = xv[k] + (q - xv[k]);  // matches reference x + (quantized - x)
    }
}

__global__ __launch_bounds__(256) void e8_quant_kernel(
    const float* __restrict__ x, float* __restrict__ out, int n)
{
    const int t  = blockIdx.x * blockDim.x + threadIdx.x;
    const int p0 = t * 2;
    const int p1 = p0 + 1;
    if (p0 >= n) return;

    const vfloat4* __restrict__ xi = reinterpret_cast<const vfloat4*>(x);
    vfloat4* __restrict__ oo = reinterpret_cast<vfloat4*>(out);

    // Issue all loads before any compute (MLP).
    const bool has1 = (p1 < n);
    const vfloat4 a0 = xi[p0 * 2 + 0];
    const vfloat4 a1 = xi[p0 * 2 + 1];
    const vfloat4 b0 = has1 ? xi[p1 * 2 + 0] : a0;
    const vfloat4 b1 = has1 ? xi[p1 * 2 + 1] : a1;

    float xva[8] = {a0.x, a0.y, a0.z, a0.w, a1.x, a1.y, a1.z, a1.w};
    float xvb[8] = {b0.x, b0.y, b0.z, b0.w, b1.x, b1.y, b1.z, b1.w};

    float ova[8], ovb[8];
    e8_point(xva, ova);   // two independent chains; compiler interleaves
    e8_point(xvb, ovb);

    vfloat4 oa = {ova[0], ova[1], ova[2], ova[3]};
    vfloat4 ob = {ova[4], ova[5], ova[6], ova[7]};
    __builtin_nontemporal_store(oa, &oo[p0 * 2 + 0]);
    __builtin_nontemporal_store(ob, &oo[p0 * 2 + 1]);
    if (has1) {
        vfloat4 oc = {ovb[0], ovb[1], ovb[2], ovb[3]};
        vfloat4 od = {ovb[4], ovb[5], ovb[6], ovb[7]};
        __builtin_nontemporal_store(oc, &oo[p1 * 2 + 0]);
        __builtin_nontemporal_store(od, &oo[p1 * 2 + 1]);
    }
}

extern "C" void kernel_launch(void* const* d_in, const int* in_sizes, int n_in,
                              void* d_out, int out_size, void* d_ws, size_t ws_size,
                              hipStream_t stream) {
    const float* x = (const float*)d_in[0];
    float* out = (float*)d_out;
    const int n = in_sizes[0] / 8;          // points
    const int block = 256;
    const int threads_needed = (n + 1) / 2; // 2 points per thread
    const int grid = (threads_needed + block - 1) / block;
    hipLaunchKernelGGL(e8_quant_kernel, dim3(grid), dim3(block), 0, stream, x, out, n);
}

// Round 6
// 89.399 us; speedup vs baseline: 1.2954x; 1.2954x over previous
//
#include <hip/hip_runtime.h>
#include <math.h>

// E8 quantizer, fully-factored exp + 2-points-per-thread MLP, plain stores.
// Round-5 post-mortem: nontemporal 16B stores defeated L2 write-coalescing
// (WRITE_SIZE 31.25 -> 75 MB, 2.4x amplification). This round: plain vector
// stores (L2 merges partial lines), and a split-half layout (thread t handles
// points t and t+n/2) so each load/store instruction keeps the round-3
// lane-address pattern that measured exactly 31250 KB of HBM writes.

static constexpr float TEMP = 0.3f;

typedef float vfloat4 __attribute__((ext_vector_type(4)));

__device__ __forceinline__ float fexp2(float v) { return __builtin_amdgcn_exp2f(v); }
__device__ __forceinline__ float frcp(float v) { return __builtin_amdgcn_rcpf(v); }

__device__ __forceinline__ void e8_point(const float xv[8], float outv[8]) {
    const float K  = 2.0f * 1.44269504088896340736f / TEMP;  // exp2 units
    const float Kh = 0.5f * K;
    float nrm2 = 0.f;
#pragma unroll
    for (int k = 0; k < 8; ++k) nrm2 = fmaf(xv[k], xv[k], nrm2);
    const float r  = sqrtf(nrm2);
    const float C  = -1.41421356237309515f * r * K;
    const float C2 = 0.5f * C;
    const float C4 = 0.25f * C;

    // ---- per-pair exponentials for half-roots (16 exps) ----
    float e01[4], e23[4], e45[4], e67[4];
    {
        const float u01 = xv[0] + xv[1], v01 = xv[1] - xv[0];
        const float u23 = xv[2] + xv[3], v23 = xv[3] - xv[2];
        const float u45 = xv[4] + xv[5], v45 = xv[5] - xv[4];
        const float u67 = xv[6] + xv[7], v67 = xv[7] - xv[6];
        e01[0] = fexp2(fmaf(u01, Kh, C4)); e01[3] = fexp2(fmaf(-u01, Kh, C4));
        e01[1] = fexp2(fmaf(v01, Kh, C4)); e01[2] = fexp2(fmaf(-v01, Kh, C4));
        e23[0] = fexp2(fmaf(u23, Kh, C4)); e23[3] = fexp2(fmaf(-u23, Kh, C4));
        e23[1] = fexp2(fmaf(v23, Kh, C4)); e23[2] = fexp2(fmaf(-v23, Kh, C4));
        e45[0] = fexp2(fmaf(u45, Kh, C4)); e45[3] = fexp2(fmaf(-u45, Kh, C4));
        e45[1] = fexp2(fmaf(v45, Kh, C4)); e45[2] = fexp2(fmaf(-v45, Kh, C4));
        e67[0] = fexp2(fmaf(u67, Kh, C4)); e67[3] = fexp2(fmaf(-u67, Kh, C4));
        e67[1] = fexp2(fmaf(v67, Kh, C4)); e67[2] = fexp2(fmaf(-v67, Kh, C4));
    }

    const float G01e = e01[0] + e01[3], G01o = e01[1] + e01[2];
    const float G23e = e23[0] + e23[3], G23o = e23[1] + e23[2];
    const float G45e = e45[0] + e45[3], G45o = e45[1] + e45[2];
    const float G67e = e67[0] + e67[3], G67o = e67[1] + e67[2];
    const float dA01 = e01[0] - e01[3], dB01 = e01[2] - e01[1];
    const float dA23 = e23[0] - e23[3], dB23 = e23[2] - e23[1];
    const float dA45 = e45[0] - e45[3], dB45 = e45[2] - e45[1];
    const float dA67 = e67[0] - e67[3], dB67 = e67[2] - e67[1];

    const float SAe = fmaf(G01e, G23e, G01o * G23o);
    const float SAo = fmaf(G01e, G23o, G01o * G23e);
    const float SBe = fmaf(G45e, G67e, G45o * G67o);
    const float SBo = fmaf(G45e, G67o, G45o * G67e);
    const float s2sum = fmaf(SAe, SBe, SAo * SBo);

    const float M01e = fmaf(G23e, SBe, G23o * SBo), M01o = fmaf(G23e, SBo, G23o * SBe);
    const float M23e = fmaf(G01e, SBe, G01o * SBo), M23o = fmaf(G01e, SBo, G01o * SBe);
    const float M45e = fmaf(G67e, SAe, G67o * SAo), M45o = fmaf(G67e, SAo, G67o * SAe);
    const float M67e = fmaf(G45e, SAe, G45o * SAo), M67o = fmaf(G45e, SAo, G45o * SAe);

    float comp[8];
    {
        const float t0 = dA01 * M01e, t1 = dB01 * M01o;
        comp[0] = t0 + t1; comp[1] = t0 - t1;
        const float t2 = dA23 * M23e, t3 = dB23 * M23o;
        comp[2] = t2 + t3; comp[3] = t2 - t3;
        const float t4 = dA45 * M45e, t5 = dB45 * M45o;
        comp[4] = t4 + t5; comp[5] = t4 - t5;
        const float t6 = dA67 * M67e, t7 = dB67 * M67o;
        comp[6] = t6 + t7; comp[7] = t6 - t7;
    }

    // ---- 112 integer roots via 16 factored exps ----
    float P[8], D[8];
#pragma unroll
    for (int i = 0; i < 8; ++i) {
        const float ep = fexp2(fmaf(xv[i],  K, C2));
        const float em = fexp2(fmaf(-xv[i], K, C2));
        P[i] = ep + em;
        D[i] = ep - em;
    }
    float suf[9];
    suf[8] = 0.f;
#pragma unroll
    for (int i = 7; i >= 0; --i) suf[i] = suf[i + 1] + P[i];
    float pre = 0.f, ssum_int = 0.f;
    float acc[8];
#pragma unroll
    for (int i = 0; i < 8; ++i) {
        const float Q = pre + suf[i + 1];             // sum_{j != i} P[j]
        acc[i] = D[i] * Q;
        ssum_int = fmaf(P[i], suf[i + 1], ssum_int);  // sum_{i<j} P_i P_j
        pre += P[i];
    }

    const float ssum = ssum_int + s2sum;
    const float inv  = frcp(ssum);
#pragma unroll
    for (int k = 0; k < 8; ++k) {
        const float total = fmaf(0.5f, comp[k], acc[k]);
        const float q = total * inv;
        outv[k] = xv[k] + (q - xv[k]);  // matches reference x + (quantized - x)
    }
}

__global__ __launch_bounds__(256) void e8_quant_kernel(
    const float* __restrict__ x, float* __restrict__ out, int n, int half)
{
    const int t = blockIdx.x * blockDim.x + threadIdx.x;
    if (t >= half) return;
    const int p0 = t;          // first half
    const int p1 = t + half;   // second half (same lane-address pattern)

    const vfloat4* __restrict__ xi = reinterpret_cast<const vfloat4*>(x);
    vfloat4* __restrict__ oo = reinterpret_cast<vfloat4*>(out);

    // Issue all loads before any compute (MLP).
    const bool has1 = (p1 < n);
    const vfloat4 a0 = xi[p0 * 2 + 0];
    const vfloat4 a1 = xi[p0 * 2 + 1];
    const vfloat4 b0 = has1 ? xi[p1 * 2 + 0] : a0;
    const vfloat4 b1 = has1 ? xi[p1 * 2 + 1] : a1;

    float xva[8] = {a0.x, a0.y, a0.z, a0.w, a1.x, a1.y, a1.z, a1.w};
    float xvb[8] = {b0.x, b0.y, b0.z, b0.w, b1.x, b1.y, b1.z, b1.w};

    float ova[8], ovb[8];
    e8_point(xva, ova);   // two independent chains; compiler interleaves
    e8_point(xvb, ovb);

    vfloat4 oa = {ova[0], ova[1], ova[2], ova[3]};
    vfloat4 ob = {ova[4], ova[5], ova[6], ova[7]};
    oo[p0 * 2 + 0] = oa;
    oo[p0 * 2 + 1] = ob;
    if (has1) {
        vfloat4 oc = {ovb[0], ovb[1], ovb[2], ovb[3]};
        vfloat4 od = {ovb[4], ovb[5], ovb[6], ovb[7]};
        oo[p1 * 2 + 0] = oc;
        oo[p1 * 2 + 1] = od;
    }
}

extern "C" void kernel_launch(void* const* d_in, const int* in_sizes, int n_in,
                              void* d_out, int out_size, void* d_ws, size_t ws_size,
                              hipStream_t stream) {
    const float* x = (const float*)d_in[0];
    float* out = (float*)d_out;
    const int n = in_sizes[0] / 8;   // points
    const int half = (n + 1) / 2;    // threads; thread t does t and t+half
    const int block = 256;
    const int grid = (half + block - 1) / block;
    hipLaunchKernelGGL(e8_quant_kernel, dim3(grid), dim3(block), 0, stream, x, out, n, half);
}

// Round 7
// 83.770 us; speedup vs baseline: 1.3824x; 1.0672x over previous
//
#include <hip/hip_runtime.h>
#include <math.h>

// E8 quantizer — round-3 structure (1 point/thread, plain vector loads/stores)
// + epilogue trim. Post-mortems baked in:
//  - r5: nontemporal 16B stores defeat L2 write-merge (WRITE_SIZE 31->75 MB). Plain stores.
//  - r6: 2-pt/thread gets serialized by the compiler (VGPR=36), halves TLP. 1 pt/thread.
//  - here: emit q directly instead of x+(q-x) (diff <= 1 ulp of |x|), -16 VALU/pt.
// Math: logit = K*dot + C (exp2 units), K=2*log2(e)/T, C=-sqrt(2)*|x|*K.
// 32 exp2/pt: integer roots via per-coord factored exps + positive
// prefix/suffix sums; half roots via per-pair exps + parity-factored sums.

static constexpr float TEMP = 0.3f;

typedef float vfloat4 __attribute__((ext_vector_type(4)));

__device__ __forceinline__ float fexp2(float v) { return __builtin_amdgcn_exp2f(v); }
__device__ __forceinline__ float frcp(float v) { return __builtin_amdgcn_rcpf(v); }

__global__ __launch_bounds__(256, 8) void e8_quant_kernel(
    const float* __restrict__ x, float* __restrict__ out, int n)
{
    const int tid = blockIdx.x * blockDim.x + threadIdx.x;
    if (tid >= n) return;

    const vfloat4* __restrict__ xi = reinterpret_cast<const vfloat4*>(x);
    vfloat4* __restrict__ oo = reinterpret_cast<vfloat4*>(out);

    const vfloat4 xa = xi[tid * 2 + 0];
    const vfloat4 xb = xi[tid * 2 + 1];
    float xv[8] = {xa.x, xa.y, xa.z, xa.w, xb.x, xb.y, xb.z, xb.w};

    const float K  = 2.0f * 1.44269504088896340736f / TEMP;  // exp2 units
    const float Kh = 0.5f * K;
    float nrm2 = 0.f;
#pragma unroll
    for (int k = 0; k < 8; ++k) nrm2 = fmaf(xv[k], xv[k], nrm2);
    const float r  = sqrtf(nrm2);
    const float C  = -1.41421356237309515f * r * K;
    const float C2 = 0.5f * C;
    const float C4 = 0.25f * C;

    // ---- per-pair exponentials for half-roots (16 exps) ----
    float e01[4], e23[4], e45[4], e67[4];
    {
        const float u01 = xv[0] + xv[1], v01 = xv[1] - xv[0];
        const float u23 = xv[2] + xv[3], v23 = xv[3] - xv[2];
        const float u45 = xv[4] + xv[5], v45 = xv[5] - xv[4];
        const float u67 = xv[6] + xv[7], v67 = xv[7] - xv[6];
        e01[0] = fexp2(fmaf(u01, Kh, C4)); e01[3] = fexp2(fmaf(-u01, Kh, C4));
        e01[1] = fexp2(fmaf(v01, Kh, C4)); e01[2] = fexp2(fmaf(-v01, Kh, C4));
        e23[0] = fexp2(fmaf(u23, Kh, C4)); e23[3] = fexp2(fmaf(-u23, Kh, C4));
        e23[1] = fexp2(fmaf(v23, Kh, C4)); e23[2] = fexp2(fmaf(-v23, Kh, C4));
        e45[0] = fexp2(fmaf(u45, Kh, C4)); e45[3] = fexp2(fmaf(-u45, Kh, C4));
        e45[1] = fexp2(fmaf(v45, Kh, C4)); e45[2] = fexp2(fmaf(-v45, Kh, C4));
        e67[0] = fexp2(fmaf(u67, Kh, C4)); e67[3] = fexp2(fmaf(-u67, Kh, C4));
        e67[1] = fexp2(fmaf(v67, Kh, C4)); e67[2] = fexp2(fmaf(-v67, Kh, C4));
    }

    const float G01e = e01[0] + e01[3], G01o = e01[1] + e01[2];
    const float G23e = e23[0] + e23[3], G23o = e23[1] + e23[2];
    const float G45e = e45[0] + e45[3], G45o = e45[1] + e45[2];
    const float G67e = e67[0] + e67[3], G67o = e67[1] + e67[2];
    const float dA01 = e01[0] - e01[3], dB01 = e01[2] - e01[1];
    const float dA23 = e23[0] - e23[3], dB23 = e23[2] - e23[1];
    const float dA45 = e45[0] - e45[3], dB45 = e45[2] - e45[1];
    const float dA67 = e67[0] - e67[3], dB67 = e67[2] - e67[1];

    const float SAe = fmaf(G01e, G23e, G01o * G23o);
    const float SAo = fmaf(G01e, G23o, G01o * G23e);
    const float SBe = fmaf(G45e, G67e, G45o * G67o);
    const float SBo = fmaf(G45e, G67o, G45o * G67e);
    const float s2sum = fmaf(SAe, SBe, SAo * SBo);

    const float M01e = fmaf(G23e, SBe, G23o * SBo), M01o = fmaf(G23e, SBo, G23o * SBe);
    const float M23e = fmaf(G01e, SBe, G01o * SBo), M23o = fmaf(G01e, SBo, G01o * SBe);
    const float M45e = fmaf(G67e, SAe, G67o * SAo), M45o = fmaf(G67e, SAo, G67o * SAe);
    const float M67e = fmaf(G45e, SAe, G45o * SAo), M67o = fmaf(G45e, SAo, G45o * SAe);

    float comp[8];
    {
        const float t0 = dA01 * M01e, t1 = dB01 * M01o;
        comp[0] = t0 + t1; comp[1] = t0 - t1;
        const float t2 = dA23 * M23e, t3 = dB23 * M23o;
        comp[2] = t2 + t3; comp[3] = t2 - t3;
        const float t4 = dA45 * M45e, t5 = dB45 * M45o;
        comp[4] = t4 + t5; comp[5] = t4 - t5;
        const float t6 = dA67 * M67e, t7 = dB67 * M67o;
        comp[6] = t6 + t7; comp[7] = t6 - t7;
    }

    // ---- 112 integer roots via 16 factored exps ----
    float P[8], D[8];
#pragma unroll
    for (int i = 0; i < 8; ++i) {
        const float ep = fexp2(fmaf(xv[i],  K, C2));
        const float em = fexp2(fmaf(-xv[i], K, C2));
        P[i] = ep + em;
        D[i] = ep - em;
    }
    float suf[9];
    suf[8] = 0.f;
#pragma unroll
    for (int i = 7; i >= 0; --i) suf[i] = suf[i + 1] + P[i];
    float pre = 0.f, ssum_int = 0.f;
    float acc[8];
#pragma unroll
    for (int i = 0; i < 8; ++i) {
        const float Q = pre + suf[i + 1];             // sum_{j != i} P[j]
        acc[i] = D[i] * Q;
        ssum_int = fmaf(P[i], suf[i + 1], ssum_int);  // sum_{i<j} P_i P_j
        pre += P[i];
    }

    const float ssum = ssum_int + s2sum;
    const float inv  = frcp(ssum);
    float outv[8];
#pragma unroll
    for (int k = 0; k < 8; ++k) {
        const float total = fmaf(0.5f, comp[k], acc[k]);
        outv[k] = total * inv;  // == x + (q - x) to <=1 ulp of |x|; thr 2e-2
    }
    vfloat4 oa = {outv[0], outv[1], outv[2], outv[3]};
    vfloat4 ob = {outv[4], outv[5], outv[6], outv[7]};
    oo[tid * 2 + 0] = oa;
    oo[tid * 2 + 1] = ob;
}

extern "C" void kernel_launch(void* const* d_in, const int* in_sizes, int n_in,
                              void* d_out, int out_size, void* d_ws, size_t ws_size,
                              hipStream_t stream) {
    const float* x = (const float*)d_in[0];
    float* out = (float*)d_out;
    const int n = in_sizes[0] / 8;   // points
    const int block = 256;
    const int grid = (n + block - 1) / block;
    hipLaunchKernelGGL(e8_quant_kernel, dim3(grid), dim3(block), 0, stream, x, out, n);
}